// Round 22
// baseline (274.902 us; speedup 1.0000x reference)
//
#include <hip/hip_runtime.h>

#define NTOK 15
#define DP   128
#define DM   768
#define NH   4
#define HD   192
#define NP   64
#define EPSF 1e-5f
#define KW2  384    // [attn(256) | pe(128)]
#define ABSTR 528   // phaseA attn LDS row stride in bytes

typedef __attribute__((ext_vector_type(8))) short bf16x8;   // 8 bf16 = 4 VGPR
typedef __attribute__((ext_vector_type(4))) float f32x4;
typedef __attribute__((ext_vector_type(4))) unsigned short us4;

__device__ __forceinline__ unsigned short f2bf(float x) {
    unsigned u = __float_as_uint(x);
    u = (u + 0x7FFF + ((u >> 16) & 1)) >> 16;   // RNE
    return (unsigned short)u;
}
// swizzled LDS byte addresses (row stride 256B)
__device__ __forceinline__ int swzP(int row, int b) { return row * 256 + (b ^ ((row & 7) << 4)); }

// ---------------------------------------------------------------------------
// P1 (merged kv+fold): blocks 0..255 (hp) recompute their own K/V 192-slices
// from protos, then fold into KWb/kqb/Wcat. Blocks 256..639: wp -> Wcat.
// r22 change: unroll-8 on the three latency-chained inner loops.
// ---------------------------------------------------------------------------
__global__ __launch_bounds__(256) void fold_kernel(
    const float* __restrict__ protos,
    const float* __restrict__ wk, const float* __restrict__ bk,
    const float* __restrict__ wv, const float* __restrict__ bv,
    const float* __restrict__ wq, const float* __restrict__ bq,
    const float* __restrict__ wo, const float* __restrict__ wp,
    unsigned short* __restrict__ KWb, float* __restrict__ kqb,
    unsigned short* __restrict__ Wcat)
{
    int b = blockIdx.x, tid = threadIdx.x;
    if (b >= 256) {
        int idx = (b - 256) * 256 + tid;
        int j = idx >> 7, d = idx & 127;
        Wcat[(size_t)j * KW2 + 256 + d] = f2bf(wp[d * DM + j]);
        return;
    }
    int hp = b, h = hp >> 6, p = hp & 63;
    __shared__ float prow[DM];
    __shared__ float Kl[HD], Vl[HD];
    for (int i = tid; i < DM; i += 256) prow[i] = protos[p * DM + i];
    __syncthreads();
    if (tid < HD) {
        float aK = bk[h * HD + tid], aV = bv[h * HD + tid];
        #pragma unroll 8
        for (int e = 0; e < DM; ++e) {
            float pr = prow[e];
            aK += pr * wk[e * DM + h * HD + tid];
            aV += pr * wv[e * DM + h * HD + tid];
        }
        Kl[tid] = aK;
        Vl[tid] = aV;
    }
    __syncthreads();
    const float scale = 0.07216878364870323f;   // 1/sqrt(192)
    if (tid < DP) {
        float a = 0.f;
        #pragma unroll 8
        for (int l = 0; l < HD; ++l) a += wq[tid * DM + h * HD + l] * Kl[l];
        KWb[hp * DP + tid] = f2bf(scale * a);
    } else if (tid == DP) {
        float a = 0.f;
        for (int l = 0; l < HD; ++l) a += bq[h * HD + l] * Kl[l];
        kqb[hp] = scale * a;
    }
    for (int jj = 0; jj < 3; ++jj) {
        int j = jj * 256 + tid;
        float a = 0.f;
        #pragma unroll 8
        for (int l = 0; l < HD; ++l) a += wo[(h * HD + l) * DM + j] * Vl[l];
        Wcat[(size_t)j * KW2 + hp] = f2bf(a);
    }
}

// ---------------------------------------------------------------------------
// Phase A (r18-verified, frozen): 2 state-rows (32 token-rows) per block.
// ---------------------------------------------------------------------------
__global__ __launch_bounds__(256, 4) void phaseA_kernel(
    const float* __restrict__ state,
    const float* __restrict__ w_scalar, const float* __restrict__ b_scalar,
    const float* __restrict__ w_patch,  const float* __restrict__ b_patch,
    const float* __restrict__ feat_emb,
    const float* __restrict__ pn_g, const float* __restrict__ pn_b,
    const unsigned short* __restrict__ KWb, const float* __restrict__ kqb,
    unsigned short* __restrict__ abufG, int Nrows)
{
    int tid = threadIdx.x;
    int w = tid >> 6, lane = tid & 63;
    int kg = lane >> 4, lr = lane & 15;
    int nb = blockIdx.x;
    size_t rowbase = (size_t)nb * 32;

    __shared__ __align__(16) char buf0[32 * ABSTR];
    __shared__ __align__(16) char pebf[32 * 256];
    __shared__ float srow[72];

    float* peF = (float*)buf0;

    if (tid < 72) {
        int rr = tid / 36;
        int gr = nb * 2 + rr;
        srow[tid] = (gr < Nrows) ? state[(size_t)gr * 36 + (tid - rr * 36)] : 0.f;
    }
    __syncthreads();

    #pragma unroll
    for (int it = 0; it < 16; ++it) {
        int idx = it * 256 + tid;
        int row = idx >> 7, d = idx & 127;
        int t = row & 15;
        const float* sr = &srow[(row >> 4) * 36];
        float val;
        if (t == 15) {
            val = 0.f;
        } else if (t == 0) {
            val = sr[5]  * w_scalar[0 * DP + d] + b_scalar[0 * DP + d] + feat_emb[0 * DP + d];
        } else if (t == 1) {
            val = sr[11] * w_scalar[1 * DP + d] + b_scalar[1 * DP + d] + feat_emb[1 * DP + d];
        } else if (t == 14) {
            val = sr[35] * w_scalar[2 * DP + d] + b_scalar[2 * DP + d] + feat_emb[5 * DP + d];
        } else {
            int f = (t - 2) / 4;
            int k = (t - 2) % 4;
            const float* pr = &sr[(2 + f) * 6];
            float acc = b_patch[f * DP + d] + feat_emb[(2 + f) * DP + d];
            for (int p = 0; p < 3; ++p) acc += pr[k + p] * w_patch[(f * 3 + p) * DP + d];
            val = acc;
        }
        peF[row * DP + d] = val;
    }
    __syncthreads();

    {
        int g = tid >> 3, ln = tid & 7;
        int t = g & 15;
        int gr = nb * 2 + (g >> 4);
        if (t == 15 || gr >= Nrows) {
            for (int d = ln; d < DP; d += 8)
                *(unsigned short*)(pebf + swzP(g, d * 2)) = 0;
        } else {
            float s = 0.f, s2 = 0.f;
            for (int d = ln; d < DP; d += 8) { float x = peF[g * DP + d]; s += x; s2 += x * x; }
            for (int off = 4; off; off >>= 1) {
                s  += __shfl_xor(s,  off, 64);
                s2 += __shfl_xor(s2, off, 64);
            }
            float m   = s / DP;
            float var = s2 / DP - m * m;
            float rin = 1.0f / sqrtf(var + EPSF);
            for (int d = ln; d < DP; d += 8) {
                float x = (peF[g * DP + d] - m) * rin * pn_g[d] + pn_b[d];
                *(unsigned short*)(pebf + swzP(g, d * 2)) = f2bf(x);
            }
        }
    }
    __syncthreads();   // peF dead; buf0 becomes attn bf16 (stride ABSTR)

    {
        const int h = w;
        const unsigned short* kwh = KWb + (size_t)h * NP * DP;
        bf16x8 ka[4][4];
        float4 kqv[4];
        #pragma unroll
        for (int Mt = 0; Mt < 4; ++Mt) {
            #pragma unroll
            for (int kk = 0; kk < 4; ++kk)
                ka[Mt][kk] = *(const bf16x8*)(kwh + (Mt * 16 + lr) * DP + kk * 32 + kg * 8);
            kqv[Mt] = *(const float4*)(kqb + h * 64 + Mt * 16 + kg * 4);
        }
        #pragma unroll
        for (int Ntl = 0; Ntl < 2; ++Ntl) {
            bf16x8 qb[4];
            #pragma unroll
            for (int kk = 0; kk < 4; ++kk)
                qb[kk] = *(const bf16x8*)(pebf + swzP(Ntl * 16 + lr, (kk * 32 + kg * 8) * 2));
            f32x4 sacc[4];
            #pragma unroll
            for (int Mt = 0; Mt < 4; ++Mt) sacc[Mt] = (f32x4){0.f, 0.f, 0.f, 0.f};
            #pragma unroll
            for (int kk = 0; kk < 4; ++kk)
                #pragma unroll
                for (int Mt = 0; Mt < 4; ++Mt)
                    sacc[Mt] = __builtin_amdgcn_mfma_f32_16x16x32_bf16(ka[Mt][kk], qb[kk], sacc[Mt], 0, 0, 0);
            #pragma unroll
            for (int Mt = 0; Mt < 4; ++Mt) {
                sacc[Mt][0] += kqv[Mt].x; sacc[Mt][1] += kqv[Mt].y;
                sacc[Mt][2] += kqv[Mt].z; sacc[Mt][3] += kqv[Mt].w;
            }
            float mx = -3.4e38f;
            #pragma unroll
            for (int Mt = 0; Mt < 4; ++Mt)
                #pragma unroll
                for (int r = 0; r < 4; ++r) mx = fmaxf(mx, sacc[Mt][r]);
            mx = fmaxf(mx, __shfl_xor(mx, 16, 64));
            mx = fmaxf(mx, __shfl_xor(mx, 32, 64));
            float sum = 0.f;
            f32x4 ee[4];
            #pragma unroll
            for (int Mt = 0; Mt < 4; ++Mt)
                #pragma unroll
                for (int r = 0; r < 4; ++r) { float e = __expf(sacc[Mt][r] - mx); ee[Mt][r] = e; sum += e; }
            sum += __shfl_xor(sum, 16, 64);
            sum += __shfl_xor(sum, 32, 64);
            float inv = 1.0f / sum;
            int row = Ntl * 16 + lr;
            #pragma unroll
            for (int Mt = 0; Mt < 4; ++Mt) {
                us4 v = { f2bf(ee[Mt][0] * inv), f2bf(ee[Mt][1] * inv),
                          f2bf(ee[Mt][2] * inv), f2bf(ee[Mt][3] * inv) };
                *(us4*)(buf0 + row * ABSTR + (h * 64 + Mt * 16 + kg * 4) * 2) = v;
            }
        }
    }
    __syncthreads();

    #pragma unroll
    for (int c = 0; c < 6; ++c) {
        int idx = c * 256 + tid;
        int row = idx / 48, chunk = idx % 48;
        bf16x8 v;
        if (chunk < 32) v = *(const bf16x8*)(buf0 + row * ABSTR + chunk * 16);
        else            v = *(const bf16x8*)(pebf + swzP(row, (chunk - 32) * 16));
        *(bf16x8*)(abufG + (rowbase + row) * KW2 + chunk * 8) = v;
    }
}

// ---------------------------------------------------------------------------
// Phase B (FROZEN r18 config — verified optimum): out = LN(A @ Wcat^T + bias).
// 2 blocks/CU is L2-capacity-pinned: 64 blocks/XCD x 48KB A + Wcat 0.58MB +
// write lines = 4MB per-XCD L2. r12/r13/r19/r20 all proved >2 blocks thrashes.
// ---------------------------------------------------------------------------
__global__ __launch_bounds__(512, 2) void phaseB_kernel(
    const unsigned short* __restrict__ abufG,
    const unsigned short* __restrict__ Wcat,
    const float* __restrict__ bp, const float* __restrict__ bo,
    const float* __restrict__ on_g, const float* __restrict__ on_b,
    float* __restrict__ out, int Nrows)
{
    int tid = threadIdx.x;
    int w = tid >> 6, lane = tid & 63;
    int kg = lane >> 4, lr = lane & 15;
    int nb = blockIdx.x;
    const int n0 = w * 96;

    __shared__ __align__(16) float stage[16 * 772];      // 49.4KB
    __shared__ float redS[8][64], redS2[8][64];

    const unsigned short* aptr = abufG + (size_t)nb * 64 * KW2;

    float gcol[6], bcol[6];
    f32x4 acc[6][4];
    #pragma unroll
    for (int nt = 0; nt < 6; ++nt) {
        int col = n0 + nt * 16 + lr;
        gcol[nt] = on_g[col]; bcol[nt] = on_b[col];
        float bias = bo[col] + bp[col];
        #pragma unroll
        for (int Mt = 0; Mt < 4; ++Mt) acc[nt][Mt] = (f32x4){bias, bias, bias, bias};
    }

    // ---- K-loop: 12 steps, fully unrolled, no barriers -------------------
    #pragma unroll
    for (int ks = 0; ks < 12; ++ks) {
        bf16x8 aw[4];
        #pragma unroll
        for (int Mt = 0; Mt < 4; ++Mt)
            aw[Mt] = *(const bf16x8*)(aptr + (Mt * 16 + lr) * KW2 + ks * 32 + kg * 8);
        __builtin_amdgcn_s_setprio(1);
        #pragma unroll
        for (int nt = 0; nt < 6; ++nt) {
            bf16x8 b = *(const bf16x8*)(Wcat + (size_t)(n0 + nt * 16 + lr) * KW2 + ks * 32 + kg * 8);
            #pragma unroll
            for (int Mt = 0; Mt < 4; ++Mt)
                acc[nt][Mt] = __builtin_amdgcn_mfma_f32_16x16x32_bf16(aw[Mt], b, acc[nt][Mt], 0, 0, 0);
        }
        __builtin_amdgcn_s_setprio(0);
    }

    // ---- LN stats --------------------------------------------------------
    #pragma unroll
    for (int Mt = 0; Mt < 4; ++Mt)
        #pragma unroll
        for (int r = 0; r < 4; ++r) {
            float s = 0.f, q = 0.f;
            #pragma unroll
            for (int nt = 0; nt < 6; ++nt) { float v = acc[nt][Mt][r]; s += v; q += v * v; }
            #pragma unroll
            for (int off = 8; off; off >>= 1) {
                s += __shfl_xor(s, off, 64);
                q += __shfl_xor(q, off, 64);
            }
            if (lr == 0) {
                int tok = Mt * 16 + kg * 4 + r;
                redS [w][tok] = s;
                redS2[w][tok] = q;
            }
        }
    __syncthreads();
    float mA[4][4], riA[4][4];
    #pragma unroll
    for (int Mt = 0; Mt < 4; ++Mt)
        #pragma unroll
        for (int r = 0; r < 4; ++r) {
            int tok = Mt * 16 + kg * 4 + r;
            float ts = 0.f, tq = 0.f;
            #pragma unroll
            for (int ww = 0; ww < 8; ++ww) { ts += redS[ww][tok]; tq += redS2[ww][tok]; }
            float mm  = ts / DM;
            float var = tq / DM - mm * mm;
            mA[Mt][r]  = mm;
            riA[Mt][r] = 1.0f / sqrtf(var + EPSF);
        }

    // ---- staged coalesced write: one 16-row tile (= one source row) at a time
    #pragma unroll
    for (int Mt = 0; Mt < 4; ++Mt) {
        __syncthreads();
        #pragma unroll
        for (int nt = 0; nt < 6; ++nt)
            #pragma unroll
            for (int r = 0; r < 4; ++r)
                stage[(kg * 4 + r) * 772 + n0 + nt * 16 + lr] =
                    (acc[nt][Mt][r] - mA[Mt][r]) * riA[Mt][r] * gcol[nt] + bcol[nt];
        __syncthreads();
        int gr = nb * 4 + Mt;
        if (gr < Nrows) {
            #pragma unroll
            for (int v = 0; v < 6; ++v) {
                int f = v * 512 + tid;          // 0..3071
                int row = f / 192, c4 = f - row * 192;
                if (row < NTOK)
                    *(float4*)(out + ((size_t)gr * NTOK + row) * DM + c4 * 4) =
                        *(const float4*)(&stage[row * 772 + c4 * 4]);
            }
        }
    }
}

extern "C" void kernel_launch(void* const* d_in, const int* in_sizes, int n_in,
                              void* d_out, int out_size, void* d_ws, size_t ws_size,
                              hipStream_t stream) {
    const float* state    = (const float*)d_in[0];
    const float* w_scalar = (const float*)d_in[1];
    const float* b_scalar = (const float*)d_in[2];
    const float* w_patch  = (const float*)d_in[3];
    const float* b_patch  = (const float*)d_in[4];
    const float* feat_emb = (const float*)d_in[5];
    const float* pn_g     = (const float*)d_in[6];
    const float* pn_b     = (const float*)d_in[7];
    const float* wq       = (const float*)d_in[8];
    const float* bq       = (const float*)d_in[9];
    const float* wk       = (const float*)d_in[10];
    const float* bk       = (const float*)d_in[11];
    const float* wv       = (const float*)d_in[12];
    const float* bv       = (const float*)d_in[13];
    const float* wp       = (const float*)d_in[14];
    const float* bp       = (const float*)d_in[15];
    const float* wo       = (const float*)d_in[16];
    const float* bo       = (const float*)d_in[17];
    const float* on_g     = (const float*)d_in[18];
    const float* on_b     = (const float*)d_in[19];
    const float* protos   = (const float*)d_in[20];
    float* out = (float*)d_out;

    float*          kqbp  = (float*)d_ws;                   // 256 f32
    unsigned short* KWb   = (unsigned short*)(kqbp + 256);  // 256*128 bf16
    unsigned short* Wcat  = KWb + 256 * DP;                 // 768*384 bf16
    unsigned short* abufG = Wcat + (size_t)DM * KW2;

    int N = in_sizes[0] / 36;
    int nblkA = (N + 1) / 2;
    int nblkB = (N + 3) / 4;
    size_t tokrows = (size_t)nblkB * 64;
    size_t need = 1024ull + 65536ull + 589824ull + tokrows * KW2 * 2ull;

    hipLaunchKernelGGL(fold_kernel, dim3(640), dim3(256), 0, stream,
                       protos, wk, bk, wv, bv, wq, bq, wo, wp,
                       KWb, kqbp, Wcat);
    if (ws_size >= need) {
        hipLaunchKernelGGL(phaseA_kernel, dim3(nblkA), dim3(256), 0, stream,
                           state, w_scalar, b_scalar, w_patch, b_patch, feat_emb,
                           pn_g, pn_b, KWb, kqbp, abufG, N);
        hipLaunchKernelGGL(phaseB_kernel, dim3(nblkB), dim3(512), 0, stream,
                           abufG, Wcat, bp, bo, on_g, on_b, out, N);
    }
}

// Round 23
// 264.066 us; speedup vs baseline: 1.0410x; 1.0410x over previous
//
#include <hip/hip_runtime.h>

#define NTOK 15
#define DP   128
#define DM   768
#define NH   4
#define HD   192
#define NP   64
#define EPSF 1e-5f
#define KW2  384    // [attn(256) | pe(128)]
#define ABSTR 528   // phaseA attn LDS row stride in bytes

typedef __attribute__((ext_vector_type(8))) short bf16x8;   // 8 bf16 = 4 VGPR
typedef __attribute__((ext_vector_type(4))) float f32x4;
typedef __attribute__((ext_vector_type(4))) unsigned short us4;

__device__ __forceinline__ unsigned short f2bf(float x) {
    unsigned u = __float_as_uint(x);
    u = (u + 0x7FFF + ((u >> 16) & 1)) >> 16;   // RNE
    return (unsigned short)u;
}
// swizzled LDS byte addresses (row stride 256B)
__device__ __forceinline__ int swzP(int row, int b) { return row * 256 + (b ^ ((row & 7) << 4)); }

// ---------------------------------------------------------------------------
// P1 (merged kv+fold, r18-verified): blocks 0..255 (hp) recompute their own
// K/V 192-slices from protos, then fold into KWb/kqb/Wcat.
// Blocks 256..639: wp transpose into Wcat.
// ---------------------------------------------------------------------------
__global__ __launch_bounds__(256) void fold_kernel(
    const float* __restrict__ protos,
    const float* __restrict__ wk, const float* __restrict__ bk,
    const float* __restrict__ wv, const float* __restrict__ bv,
    const float* __restrict__ wq, const float* __restrict__ bq,
    const float* __restrict__ wo, const float* __restrict__ wp,
    unsigned short* __restrict__ KWb, float* __restrict__ kqb,
    unsigned short* __restrict__ Wcat)
{
    int b = blockIdx.x, tid = threadIdx.x;
    if (b >= 256) {
        int idx = (b - 256) * 256 + tid;
        int j = idx >> 7, d = idx & 127;
        Wcat[(size_t)j * KW2 + 256 + d] = f2bf(wp[d * DM + j]);
        return;
    }
    int hp = b, h = hp >> 6, p = hp & 63;
    __shared__ float prow[DM];
    __shared__ float Kl[HD], Vl[HD];
    for (int i = tid; i < DM; i += 256) prow[i] = protos[p * DM + i];
    __syncthreads();
    if (tid < HD) {
        float aK = bk[h * HD + tid], aV = bv[h * HD + tid];
        for (int e = 0; e < DM; ++e) {
            float pr = prow[e];
            aK += pr * wk[e * DM + h * HD + tid];
            aV += pr * wv[e * DM + h * HD + tid];
        }
        Kl[tid] = aK;
        Vl[tid] = aV;
    }
    __syncthreads();
    const float scale = 0.07216878364870323f;   // 1/sqrt(192)
    if (tid < DP) {
        float a = 0.f;
        for (int l = 0; l < HD; ++l) a += wq[tid * DM + h * HD + l] * Kl[l];
        KWb[hp * DP + tid] = f2bf(scale * a);
    } else if (tid == DP) {
        float a = 0.f;
        for (int l = 0; l < HD; ++l) a += bq[h * HD + l] * Kl[l];
        kqb[hp] = scale * a;
    }
    for (int jj = 0; jj < 3; ++jj) {
        int j = jj * 256 + tid;
        float a = 0.f;
        for (int l = 0; l < HD; ++l) a += wo[(h * HD + l) * DM + j] * Vl[l];
        Wcat[(size_t)j * KW2 + hp] = f2bf(a);
    }
}

// ---------------------------------------------------------------------------
// Phase A (r18-verified, frozen): 2 state-rows (32 token-rows) per block.
// attn lands in LDS; unified coalesced copy-out of [attn|pe] rows.
// ---------------------------------------------------------------------------
__global__ __launch_bounds__(256, 4) void phaseA_kernel(
    const float* __restrict__ state,
    const float* __restrict__ w_scalar, const float* __restrict__ b_scalar,
    const float* __restrict__ w_patch,  const float* __restrict__ b_patch,
    const float* __restrict__ feat_emb,
    const float* __restrict__ pn_g, const float* __restrict__ pn_b,
    const unsigned short* __restrict__ KWb, const float* __restrict__ kqb,
    unsigned short* __restrict__ abufG, int Nrows)
{
    int tid = threadIdx.x;
    int w = tid >> 6, lane = tid & 63;
    int kg = lane >> 4, lr = lane & 15;
    int nb = blockIdx.x;
    size_t rowbase = (size_t)nb * 32;

    __shared__ __align__(16) char buf0[32 * ABSTR];
    __shared__ __align__(16) char pebf[32 * 256];
    __shared__ float srow[72];

    float* peF = (float*)buf0;

    if (tid < 72) {
        int rr = tid / 36;
        int gr = nb * 2 + rr;
        srow[tid] = (gr < Nrows) ? state[(size_t)gr * 36 + (tid - rr * 36)] : 0.f;
    }
    __syncthreads();

    #pragma unroll
    for (int it = 0; it < 16; ++it) {
        int idx = it * 256 + tid;
        int row = idx >> 7, d = idx & 127;
        int t = row & 15;
        const float* sr = &srow[(row >> 4) * 36];
        float val;
        if (t == 15) {
            val = 0.f;
        } else if (t == 0) {
            val = sr[5]  * w_scalar[0 * DP + d] + b_scalar[0 * DP + d] + feat_emb[0 * DP + d];
        } else if (t == 1) {
            val = sr[11] * w_scalar[1 * DP + d] + b_scalar[1 * DP + d] + feat_emb[1 * DP + d];
        } else if (t == 14) {
            val = sr[35] * w_scalar[2 * DP + d] + b_scalar[2 * DP + d] + feat_emb[5 * DP + d];
        } else {
            int f = (t - 2) / 4;
            int k = (t - 2) % 4;
            const float* pr = &sr[(2 + f) * 6];
            float acc = b_patch[f * DP + d] + feat_emb[(2 + f) * DP + d];
            for (int p = 0; p < 3; ++p) acc += pr[k + p] * w_patch[(f * 3 + p) * DP + d];
            val = acc;
        }
        peF[row * DP + d] = val;
    }
    __syncthreads();

    {
        int g = tid >> 3, ln = tid & 7;
        int t = g & 15;
        int gr = nb * 2 + (g >> 4);
        if (t == 15 || gr >= Nrows) {
            for (int d = ln; d < DP; d += 8)
                *(unsigned short*)(pebf + swzP(g, d * 2)) = 0;
        } else {
            float s = 0.f, s2 = 0.f;
            for (int d = ln; d < DP; d += 8) { float x = peF[g * DP + d]; s += x; s2 += x * x; }
            for (int off = 4; off; off >>= 1) {
                s  += __shfl_xor(s,  off, 64);
                s2 += __shfl_xor(s2, off, 64);
            }
            float m   = s / DP;
            float var = s2 / DP - m * m;
            float rin = 1.0f / sqrtf(var + EPSF);
            for (int d = ln; d < DP; d += 8) {
                float x = (peF[g * DP + d] - m) * rin * pn_g[d] + pn_b[d];
                *(unsigned short*)(pebf + swzP(g, d * 2)) = f2bf(x);
            }
        }
    }
    __syncthreads();   // peF dead; buf0 becomes attn bf16 (stride ABSTR)

    {
        const int h = w;
        const unsigned short* kwh = KWb + (size_t)h * NP * DP;
        bf16x8 ka[4][4];
        float4 kqv[4];
        #pragma unroll
        for (int Mt = 0; Mt < 4; ++Mt) {
            #pragma unroll
            for (int kk = 0; kk < 4; ++kk)
                ka[Mt][kk] = *(const bf16x8*)(kwh + (Mt * 16 + lr) * DP + kk * 32 + kg * 8);
            kqv[Mt] = *(const float4*)(kqb + h * 64 + Mt * 16 + kg * 4);
        }
        #pragma unroll
        for (int Ntl = 0; Ntl < 2; ++Ntl) {
            bf16x8 qb[4];
            #pragma unroll
            for (int kk = 0; kk < 4; ++kk)
                qb[kk] = *(const bf16x8*)(pebf + swzP(Ntl * 16 + lr, (kk * 32 + kg * 8) * 2));
            f32x4 sacc[4];
            #pragma unroll
            for (int Mt = 0; Mt < 4; ++Mt) sacc[Mt] = (f32x4){0.f, 0.f, 0.f, 0.f};
            #pragma unroll
            for (int kk = 0; kk < 4; ++kk)
                #pragma unroll
                for (int Mt = 0; Mt < 4; ++Mt)
                    sacc[Mt] = __builtin_amdgcn_mfma_f32_16x16x32_bf16(ka[Mt][kk], qb[kk], sacc[Mt], 0, 0, 0);
            #pragma unroll
            for (int Mt = 0; Mt < 4; ++Mt) {
                sacc[Mt][0] += kqv[Mt].x; sacc[Mt][1] += kqv[Mt].y;
                sacc[Mt][2] += kqv[Mt].z; sacc[Mt][3] += kqv[Mt].w;
            }
            float mx = -3.4e38f;
            #pragma unroll
            for (int Mt = 0; Mt < 4; ++Mt)
                #pragma unroll
                for (int r = 0; r < 4; ++r) mx = fmaxf(mx, sacc[Mt][r]);
            mx = fmaxf(mx, __shfl_xor(mx, 16, 64));
            mx = fmaxf(mx, __shfl_xor(mx, 32, 64));
            float sum = 0.f;
            f32x4 ee[4];
            #pragma unroll
            for (int Mt = 0; Mt < 4; ++Mt)
                #pragma unroll
                for (int r = 0; r < 4; ++r) { float e = __expf(sacc[Mt][r] - mx); ee[Mt][r] = e; sum += e; }
            sum += __shfl_xor(sum, 16, 64);
            sum += __shfl_xor(sum, 32, 64);
            float inv = 1.0f / sum;
            int row = Ntl * 16 + lr;
            #pragma unroll
            for (int Mt = 0; Mt < 4; ++Mt) {
                us4 v = { f2bf(ee[Mt][0] * inv), f2bf(ee[Mt][1] * inv),
                          f2bf(ee[Mt][2] * inv), f2bf(ee[Mt][3] * inv) };
                *(us4*)(buf0 + row * ABSTR + (h * 64 + Mt * 16 + kg * 4) * 2) = v;
            }
        }
    }
    __syncthreads();

    #pragma unroll
    for (int c = 0; c < 6; ++c) {
        int idx = c * 256 + tid;
        int row = idx / 48, chunk = idx % 48;
        bf16x8 v;
        if (chunk < 32) v = *(const bf16x8*)(buf0 + row * ABSTR + chunk * 16);
        else            v = *(const bf16x8*)(pebf + swzP(row, (chunk - 32) * 16));
        *(bf16x8*)(abufG + (rowbase + row) * KW2 + chunk * 8) = v;
    }
}

// ---------------------------------------------------------------------------
// Phase B (FROZEN r18 config — verified optimum): out = LN(A @ Wcat^T + bias).
// 2 blocks/CU is L2-capacity-pinned: 64 blocks/XCD x 48KB A + Wcat 0.58MB +
// write lines = 4MB per-XCD L2. r12/r13/r19/r20 all proved >2 blocks thrashes.
// ---------------------------------------------------------------------------
__global__ __launch_bounds__(512, 2) void phaseB_kernel(
    const unsigned short* __restrict__ abufG,
    const unsigned short* __restrict__ Wcat,
    const float* __restrict__ bp, const float* __restrict__ bo,
    const float* __restrict__ on_g, const float* __restrict__ on_b,
    float* __restrict__ out, int Nrows)
{
    int tid = threadIdx.x;
    int w = tid >> 6, lane = tid & 63;
    int kg = lane >> 4, lr = lane & 15;
    int nb = blockIdx.x;
    const int n0 = w * 96;

    __shared__ __align__(16) float stage[16 * 772];      // 49.4KB
    __shared__ float redS[8][64], redS2[8][64];

    const unsigned short* aptr = abufG + (size_t)nb * 64 * KW2;

    float gcol[6], bcol[6];
    f32x4 acc[6][4];
    #pragma unroll
    for (int nt = 0; nt < 6; ++nt) {
        int col = n0 + nt * 16 + lr;
        gcol[nt] = on_g[col]; bcol[nt] = on_b[col];
        float bias = bo[col] + bp[col];
        #pragma unroll
        for (int Mt = 0; Mt < 4; ++Mt) acc[nt][Mt] = (f32x4){bias, bias, bias, bias};
    }

    // ---- K-loop: 12 steps, fully unrolled, no barriers -------------------
    #pragma unroll
    for (int ks = 0; ks < 12; ++ks) {
        bf16x8 aw[4];
        #pragma unroll
        for (int Mt = 0; Mt < 4; ++Mt)
            aw[Mt] = *(const bf16x8*)(aptr + (Mt * 16 + lr) * KW2 + ks * 32 + kg * 8);
        __builtin_amdgcn_s_setprio(1);
        #pragma unroll
        for (int nt = 0; nt < 6; ++nt) {
            bf16x8 b = *(const bf16x8*)(Wcat + (size_t)(n0 + nt * 16 + lr) * KW2 + ks * 32 + kg * 8);
            #pragma unroll
            for (int Mt = 0; Mt < 4; ++Mt)
                acc[nt][Mt] = __builtin_amdgcn_mfma_f32_16x16x32_bf16(aw[Mt], b, acc[nt][Mt], 0, 0, 0);
        }
        __builtin_amdgcn_s_setprio(0);
    }

    // ---- LN stats --------------------------------------------------------
    #pragma unroll
    for (int Mt = 0; Mt < 4; ++Mt)
        #pragma unroll
        for (int r = 0; r < 4; ++r) {
            float s = 0.f, q = 0.f;
            #pragma unroll
            for (int nt = 0; nt < 6; ++nt) { float v = acc[nt][Mt][r]; s += v; q += v * v; }
            #pragma unroll
            for (int off = 8; off; off >>= 1) {
                s += __shfl_xor(s, off, 64);
                q += __shfl_xor(q, off, 64);
            }
            if (lr == 0) {
                int tok = Mt * 16 + kg * 4 + r;
                redS [w][tok] = s;
                redS2[w][tok] = q;
            }
        }
    __syncthreads();
    float mA[4][4], riA[4][4];
    #pragma unroll
    for (int Mt = 0; Mt < 4; ++Mt)
        #pragma unroll
        for (int r = 0; r < 4; ++r) {
            int tok = Mt * 16 + kg * 4 + r;
            float ts = 0.f, tq = 0.f;
            #pragma unroll
            for (int ww = 0; ww < 8; ++ww) { ts += redS[ww][tok]; tq += redS2[ww][tok]; }
            float mm  = ts / DM;
            float var = tq / DM - mm * mm;
            mA[Mt][r]  = mm;
            riA[Mt][r] = 1.0f / sqrtf(var + EPSF);
        }

    // ---- staged coalesced write: one 16-row tile (= one source row) at a time
    #pragma unroll
    for (int Mt = 0; Mt < 4; ++Mt) {
        __syncthreads();
        #pragma unroll
        for (int nt = 0; nt < 6; ++nt)
            #pragma unroll
            for (int r = 0; r < 4; ++r)
                stage[(kg * 4 + r) * 772 + n0 + nt * 16 + lr] =
                    (acc[nt][Mt][r] - mA[Mt][r]) * riA[Mt][r] * gcol[nt] + bcol[nt];
        __syncthreads();
        int gr = nb * 4 + Mt;
        if (gr < Nrows) {
            #pragma unroll
            for (int v = 0; v < 6; ++v) {
                int f = v * 512 + tid;          // 0..3071
                int row = f / 192, c4 = f - row * 192;
                if (row < NTOK)
                    *(float4*)(out + ((size_t)gr * NTOK + row) * DM + c4 * 4) =
                        *(const float4*)(&stage[row * 772 + c4 * 4]);
            }
        }
    }
}

extern "C" void kernel_launch(void* const* d_in, const int* in_sizes, int n_in,
                              void* d_out, int out_size, void* d_ws, size_t ws_size,
                              hipStream_t stream) {
    const float* state    = (const float*)d_in[0];
    const float* w_scalar = (const float*)d_in[1];
    const float* b_scalar = (const float*)d_in[2];
    const float* w_patch  = (const float*)d_in[3];
    const float* b_patch  = (const float*)d_in[4];
    const float* feat_emb = (const float*)d_in[5];
    const float* pn_g     = (const float*)d_in[6];
    const float* pn_b     = (const float*)d_in[7];
    const float* wq       = (const float*)d_in[8];
    const float* bq       = (const float*)d_in[9];
    const float* wk       = (const float*)d_in[10];
    const float* bk       = (const float*)d_in[11];
    const float* wv       = (const float*)d_in[12];
    const float* bv       = (const float*)d_in[13];
    const float* wp       = (const float*)d_in[14];
    const float* bp       = (const float*)d_in[15];
    const float* wo       = (const float*)d_in[16];
    const float* bo       = (const float*)d_in[17];
    const float* on_g     = (const float*)d_in[18];
    const float* on_b     = (const float*)d_in[19];
    const float* protos   = (const float*)d_in[20];
    float* out = (float*)d_out;

    float*          kqbp  = (float*)d_ws;                   // 256 f32
    unsigned short* KWb   = (unsigned short*)(kqbp + 256);  // 256*128 bf16
    unsigned short* Wcat  = KWb + 256 * DP;                 // 768*384 bf16
    unsigned short* abufG = Wcat + (size_t)DM * KW2;

    int N = in_sizes[0] / 36;
    int nblkA = (N + 1) / 2;
    int nblkB = (N + 3) / 4;
    size_t tokrows = (size_t)nblkB * 64;
    size_t need = 1024ull + 65536ull + 589824ull + tokrows * KW2 * 2ull;

    hipLaunchKernelGGL(fold_kernel, dim3(640), dim3(256), 0, stream,
                       protos, wk, bk, wv, bv, wq, bq, wo, wp,
                       KWb, kqbp, Wcat);
    if (ws_size >= need) {
        hipLaunchKernelGGL(phaseA_kernel, dim3(nblkA), dim3(256), 0, stream,
                           state, w_scalar, b_scalar, w_patch, b_patch, feat_emb,
                           pn_g, pn_b, KWb, kqbp, abufG, N);
        hipLaunchKernelGGL(phaseB_kernel, dim3(nblkB), dim3(512), 0, stream,
                           abufG, Wcat, bp, bo, on_g, on_b, out, N);
    }
}